// Round 8
// baseline (132.935 us; speedup 1.0000x reference)
//
#include <hip/hip_runtime.h>

#define N 8192
#define D 128
// (1/0.07) * log2(e): fold temperature AND base-2 conversion into A-side scale
#define SCALE_A 20.6098592f
#define T 128                 // 64-row tile groups
#define NTILE (T * (T + 1) / 2)   // 8256 upper-triangle 64x64 tiles
#define NBLK (NTILE / 4)      // 2064 blocks, 4 waves each

using short8  = __attribute__((ext_vector_type(8))) short;
using float4v = __attribute__((ext_vector_type(4))) float;

#if __has_builtin(__builtin_amdgcn_exp2f)
#define EXP2(x) __builtin_amdgcn_exp2f(x)
#else
#define EXP2(x) __expf((x) * 0.69314718f)
#endif

// float -> bf16 (RNE) as raw ushort
static __device__ inline unsigned int f2bf(float f) {
    union { float f; unsigned int u; } x;
    x.f = f;
    unsigned int u = x.u;
    return (u + 0x7FFFu + ((u >> 16) & 1u)) >> 16;
}

// Pre-pass: emb fp32 -> bf16 in MFMA FRAGMENT ORDER.
//   chunk index o = (rt*4 + ks)*64 + lane  holds
//   E[rt*16 + (lane&15)][ks*32 + (lane>>4)*8 .. +8]   (16 B = 8 bf16)
// so every A/B fragment load in cl_main is ONE coalesced 1KB wave-load.
// bfAf is prescaled by SCALE_A, bfBf unscaled. Also zeroes tot/pos/ticket.
// 512 blocks x 256 threads; reads coalesced (32B/thread), writes scattered
// 16B (L2 absorbs; 4 MB total, one-time cost).
__global__ __launch_bounds__(256) void cl_prep(
    const float* __restrict__ emb, unsigned short* __restrict__ bfBf,
    unsigned short* __restrict__ bfAf, float* __restrict__ tot,
    int* __restrict__ ticket)
{
    const int t = blockIdx.x * 256 + threadIdx.x;   // 0..131071
    const int row   = t >> 4;
    const int chunk = t & 15;
    const float* p = emb + (size_t)row * D + chunk * 8;
    float4v f0 = *(const float4v*)p;
    float4v f1 = *(const float4v*)(p + 4);
    uint4 ub, ua;
    ub.x = f2bf(f0[0]) | (f2bf(f0[1]) << 16);
    ub.y = f2bf(f0[2]) | (f2bf(f0[3]) << 16);
    ub.z = f2bf(f1[0]) | (f2bf(f1[1]) << 16);
    ub.w = f2bf(f1[2]) | (f2bf(f1[3]) << 16);
    ua.x = f2bf(f0[0] * SCALE_A) | (f2bf(f0[1] * SCALE_A) << 16);
    ua.y = f2bf(f0[2] * SCALE_A) | (f2bf(f0[3] * SCALE_A) << 16);
    ua.z = f2bf(f1[0] * SCALE_A) | (f2bf(f1[1] * SCALE_A) << 16);
    ua.w = f2bf(f1[2] * SCALE_A) | (f2bf(f1[3] * SCALE_A) << 16);
    const int rt = row >> 4, m = row & 15;
    const int ks = chunk >> 2, qq = chunk & 3;
    const int o  = ((rt * 4 + ks) << 6) + qq * 16 + m;   // fragment-order chunk
    ((uint4*)bfBf)[o] = ub;
    ((uint4*)bfAf)[o] = ua;
    if (t < 2 * N) tot[t] = 0.f;    // tot and pos are contiguous
    if (t == 0) *ticket = 0;
}

// Barrier-free, LDS-free main kernel. One 64x64 upper-triangle tile per WAVE
// (8256 tiles over T=128 row groups); 4 independent waves per block.
// All A/B fragment loads are coalesced 1KB wave-loads from the 4MB
// fragment-order pool (L2-resident). Symmetry: tile (ti,tj), ti<tj adds its
// row sums to rows of ti and col sums to rows of tj; diag adds row sums only.
// Register floor ~155 -> (256,2) proven no-spill; >=3 waves/EU spilled when
// floor was ~190 (R2/R3) — revisit only if counters show latency-bound.
// NO agent-scope fences (R4: per-block L2-invalidate thrash). Producer order =
// s_waitcnt vmcnt(0) + barrier before a RELAXED ticket add.
__global__ __launch_bounds__(256, 2) void cl_main(
    const unsigned short* __restrict__ bfAf, const unsigned short* __restrict__ bfBf,
    const int* __restrict__ labels,
    float* __restrict__ tot, float* __restrict__ pos,
    int* __restrict__ ticket, float* __restrict__ out)
{
    __shared__ float sred[2][4];
    __shared__ int s_ticket;

    const int tid  = threadIdx.x;
    const int lane = tid & 63;
    const int wave = tid >> 6;
    const int q    = lane >> 4;   // quad id 0..3
    const int c    = lane & 15;

    // ---- decode this wave's upper-triangle tile: wt -> (ti, tj), ti <= tj ----
    const int wt = blockIdx.x * 4 + wave;           // 0..8255
    int ti = (int)((257.0f - sqrtf(66049.0f - 8.0f * (float)wt)) * 0.5f);
    ti = ti < 0 ? 0 : (ti > T - 1 ? T - 1 : ti);
    while (ti > 0 && T * ti - ti * (ti - 1) / 2 > wt) --ti;
    while (T * (ti + 1) - (ti + 1) * ti / 2 <= wt) ++ti;
    const int tj   = ti + (wt - (T * ti - ti * (ti - 1) / 2));
    const bool diag = (ti == tj);
    const int rbase = ti * 64;
    const int cbase = tj * 64;

    const short8* Af = (const short8*)bfAf;
    const short8* Bf = (const short8*)bfBf;

    // ---- A fragments: 16 coalesced 1KB wave-loads, reused over 4 col-tiles ----
    short8 afrag[4][4];
    int rowlab[4][4];
    #pragma unroll
    for (int tr = 0; tr < 4; ++tr) {
        const int rt = ti * 4 + tr;                 // global 16-row tile
        #pragma unroll
        for (int ks = 0; ks < 4; ++ks)
            afrag[tr][ks] = Af[((rt * 4 + ks) << 6) + lane];
        #pragma unroll
        for (int reg = 0; reg < 4; ++reg)
            rowlab[tr][reg] = labels[rbase + tr * 16 + q * 4 + reg];
    }

    float tot_a[4][4], pos_a[4][4];
    #pragma unroll
    for (int tr = 0; tr < 4; ++tr)
        #pragma unroll
        for (int reg = 0; reg < 4; ++reg) { tot_a[tr][reg] = 0.f; pos_a[tr][reg] = 0.f; }

    #pragma unroll
    for (int tc = 0; tc < 4; ++tc) {
        const int ctile = cbase + tc * 16;
        const int lc = labels[ctile + c];

        float4v acc[4];
        #pragma unroll
        for (int tr = 0; tr < 4; ++tr) {
            float4v z = {0.f, 0.f, 0.f, 0.f};
            acc[tr] = z;
        }
        #pragma unroll
        for (int ks = 0; ks < 4; ++ks) {
            short8 b = Bf[(((tj * 4 + tc) * 4 + ks) << 6) + lane];
            #pragma unroll
            for (int tr = 0; tr < 4; ++tr)
                acc[tr] = __builtin_amdgcn_mfma_f32_16x16x32_bf16(
                    afrag[tr][ks], b, acc[tr], 0, 0, 0);
        }

        // epilogue: exp2, diagonal/label masks, row + col accumulation
        float colt = 0.f, colp = 0.f;
        #pragma unroll
        for (int tr = 0; tr < 4; ++tr) {
            const bool diag16 = diag && (tr == tc);   // wave-uniform
            #pragma unroll
            for (int reg = 0; reg < 4; ++reg) {
                float v = EXP2(acc[tr][reg]);
                if (diag16 && (q * 4 + reg) == c) v = 0.f;  // r == c
                const bool m = (rowlab[tr][reg] == lc);
                tot_a[tr][reg] += v;
                if (m) pos_a[tr][reg] += v;
                colt += v;
                if (m) colp += v;
            }
        }
        if (!diag) {
            colt += __shfl_xor(colt, 16, 64);
            colt += __shfl_xor(colt, 32, 64);
            colp += __shfl_xor(colp, 16, 64);
            colp += __shfl_xor(colp, 32, 64);
            if (q == 0) {   // lanes 0..15 hold cols ctile+c
                atomicAdd(&tot[ctile + c], colt);
                atomicAdd(&pos[ctile + c], colp);
            }
        }
    }

    // ---- row sums: reduce over the 16 column-lanes, one atomic per row ----
    #pragma unroll
    for (int tr = 0; tr < 4; ++tr)
        #pragma unroll
        for (int reg = 0; reg < 4; ++reg) {
            float tt = tot_a[tr][reg];
            float pp = pos_a[tr][reg];
            #pragma unroll
            for (int m = 1; m < 16; m <<= 1) {
                tt += __shfl_xor(tt, m, 64);
                pp += __shfl_xor(pp, m, 64);
            }
            if (c == 0) {
                const int r = rbase + tr * 16 + q * 4 + reg;
                atomicAdd(&tot[r], tt);
                atomicAdd(&pos[r], pp);
            }
        }

    // ---- last-block finalize: completion-wait + relaxed ticket (NO cache ops)
    asm volatile("s_waitcnt vmcnt(0)" ::: "memory");  // our atomics committed
    __syncthreads();
    if (tid == 0)
        s_ticket = __hip_atomic_fetch_add(ticket, 1, __ATOMIC_RELAXED,
                                          __HIP_MEMORY_SCOPE_AGENT);
    __syncthreads();
    if (s_ticket != NBLK - 1) return;

    float lsum = 0.f, lcnt = 0.f;
    #pragma unroll 4
    for (int i = tid; i < N; i += 256) {
        const float tt = __hip_atomic_load(&tot[i], __ATOMIC_RELAXED,
                                           __HIP_MEMORY_SCOPE_AGENT);
        const float pp = __hip_atomic_load(&pos[i], __ATOMIC_RELAXED,
                                           __HIP_MEMORY_SCOPE_AGENT);
        const float loss = -__logf(pp / (tt + 1e-8f) + 1e-8f);
        if (pp > 0.f) { lsum += loss; lcnt += 1.f; }   // valid <=> pos>0
    }
    #pragma unroll
    for (int m = 1; m < 64; m <<= 1) {
        lsum += __shfl_xor(lsum, m, 64);
        lcnt += __shfl_xor(lcnt, m, 64);
    }
    if (lane == 0) { sred[0][wave] = lsum; sred[1][wave] = lcnt; }
    __syncthreads();
    if (tid == 0) {
        const float s = sred[0][0] + sred[0][1] + sred[0][2] + sred[0][3];
        const float n = sred[1][0] + sred[1][1] + sred[1][2] + sred[1][3];
        out[0] = (n > 0.f) ? s / fmaxf(n, 1.f) : 0.f;
    }
}

extern "C" void kernel_launch(void* const* d_in, const int* in_sizes, int n_in,
                              void* d_out, int out_size, void* d_ws, size_t ws_size,
                              hipStream_t stream) {
    const float* emb  = (const float*)d_in[0];
    const int* labels = (const int*)d_in[1];
    unsigned short* bfBf = (unsigned short*)d_ws;                      // 2 MB
    unsigned short* bfAf = bfBf + (size_t)N * D;                       // 2 MB
    float* tot    = (float*)(bfAf + (size_t)N * D);
    float* pos    = tot + N;
    int*   ticket = (int*)(pos + N);

    cl_prep<<<512, 256, 0, stream>>>(emb, bfBf, bfAf, tot, ticket);
    cl_main<<<NBLK, 256, 0, stream>>>(bfAf, bfBf, labels, tot, pos,
                                      ticket, (float*)d_out);
}

// Round 9
// 107.244 us; speedup vs baseline: 1.2395x; 1.2395x over previous
//
#include <hip/hip_runtime.h>

#define N 8192
#define D 128
// (1/0.07) * log2(e): fold temperature AND base-2 conversion into A-side scale
#define SCALE_A 20.6098592f
#define NBX 64
#define NBY 8
#define NBLK (NBX * NBY)

using short8  = __attribute__((ext_vector_type(8))) short;
using float4v = __attribute__((ext_vector_type(4))) float;

#if __has_builtin(__builtin_amdgcn_exp2f)
#define EXP2(x) __builtin_amdgcn_exp2f(x)
#else
#define EXP2(x) __expf((x) * 0.69314718f)
#endif

// float -> bf16 (RNE) as raw ushort
static __device__ inline unsigned int f2bf(float f) {
    union { float f; unsigned int u; } x;
    x.f = f;
    unsigned int u = x.u;
    return (u + 0x7FFFu + ((u >> 16) & 1u)) >> 16;
}

// Pre-pass: emb fp32 -> bf16 in MFMA FRAGMENT ORDER (verified R8):
//   16B chunk o = (rt*4 + ks)*64 + q*16 + m  holds
//   E[rt*16 + m][ks*32 + q*8 .. +8]
// so every A/B fragment load in cl_main is ONE coalesced 1KB wave-load
// (lane = q*16 + m matches the 16x16x32 A/B operand layout m=lane&15,
//  k=(lane>>4)*8+j). bfAf prescaled by SCALE_A, bfBf unscaled.
__global__ __launch_bounds__(256) void cl_prep(
    const float* __restrict__ emb, unsigned short* __restrict__ bfBf,
    unsigned short* __restrict__ bfAf, float* __restrict__ tot,
    int* __restrict__ ticket)
{
    const int t = blockIdx.x * 256 + threadIdx.x;   // 0..131071
    const int row   = t >> 4;
    const int chunk = t & 15;
    const float* p = emb + (size_t)row * D + chunk * 8;
    float4v f0 = *(const float4v*)p;
    float4v f1 = *(const float4v*)(p + 4);
    uint4 ub, ua;
    ub.x = f2bf(f0[0]) | (f2bf(f0[1]) << 16);
    ub.y = f2bf(f0[2]) | (f2bf(f0[3]) << 16);
    ub.z = f2bf(f1[0]) | (f2bf(f1[1]) << 16);
    ub.w = f2bf(f1[2]) | (f2bf(f1[3]) << 16);
    ua.x = f2bf(f0[0] * SCALE_A) | (f2bf(f0[1] * SCALE_A) << 16);
    ua.y = f2bf(f0[2] * SCALE_A) | (f2bf(f0[3] * SCALE_A) << 16);
    ua.z = f2bf(f1[0] * SCALE_A) | (f2bf(f1[1] * SCALE_A) << 16);
    ua.w = f2bf(f1[2] * SCALE_A) | (f2bf(f1[3] * SCALE_A) << 16);
    const int rt = row >> 4, m = row & 15;
    const int ks = chunk >> 2, qq = chunk & 3;
    const int o  = ((rt * 4 + ks) << 6) + qq * 16 + m;   // fragment-order chunk
    ((uint4*)bfBf)[o] = ub;
    ((uint4*)bfAf)[o] = ua;
    if (t < 2 * N) tot[t] = 0.f;    // tot and pos are contiguous
    if (t == 0) *ticket = 0;
}

// Barrier-free, LDS-free, gather-free main kernel.
// Grid (64,8) x 256 = 2 blocks/CU (R5's proven block structure). Each wave
// owns 32 rows x 1024 cols: A-frags (8 coalesced 1KB loads) amortized over
// 8 column-iterations; per iter 32 coalesced B-frag loads (same lines for
// all 4 waves -> L1 broadcast), 64 MFMA, minimal full-matrix epilogue
// (~6 VALU/elem; symmetric variants pay the savings back in col-sum VALU +
// 2.6x atomics, R7/R8). No __syncthreads in the hot path (R5 lesson), no
// gathers (R6 lesson: row-major frag loads = 16-line gathers), no per-tile
// decode/atomic overhead (R8 lesson).
// Register floor ~160 unified -> (256,2); >=3 waves/EU spilled at ~190 floor
// (R2/R3) — revisit only with counter evidence. NO agent-scope fences (R4:
// per-block L2-invalidate thrash). Producer order = s_waitcnt vmcnt(0) +
// barrier before a RELAXED ticket add; consumer relaxed agent loads.
__global__ __launch_bounds__(256, 2) void cl_main(
    const unsigned short* __restrict__ bfAf, const unsigned short* __restrict__ bfBf,
    const int* __restrict__ labels,
    float* __restrict__ tot, float* __restrict__ pos,
    int* __restrict__ ticket, float* __restrict__ out)
{
    __shared__ float sred[2][4];
    __shared__ int s_ticket;

    const int tid  = threadIdx.x;
    const int lane = tid & 63;
    const int wave = tid >> 6;
    const int q    = lane >> 4;   // quad id 0..3
    const int c    = lane & 15;
    const int rw   = blockIdx.x * 128 + wave * 32;

    const short8* Af = (const short8*)bfAf;
    const short8* Bf = (const short8*)bfBf;

    // ---- A fragments: 8 coalesced 1KB wave-loads, reused over 1024 cols ----
    short8 afrag[2][4];
    int rowlab[2][4];
    #pragma unroll
    for (int tr = 0; tr < 2; ++tr) {
        const int rt = blockIdx.x * 8 + wave * 2 + tr;   // global 16-row tile
        #pragma unroll
        for (int ks = 0; ks < 4; ++ks)
            afrag[tr][ks] = Af[((rt * 4 + ks) << 6) + lane];
        #pragma unroll
        for (int reg = 0; reg < 4; ++reg)
            rowlab[tr][reg] = labels[rw + tr * 16 + q * 4 + reg];
    }

    float tot_a[2][4] = {{0.f,0.f,0.f,0.f},{0.f,0.f,0.f,0.f}};
    float pos_a[2][4] = {{0.f,0.f,0.f,0.f},{0.f,0.f,0.f,0.f}};

    for (int it = 0; it < 8; ++it) {
        const int cbase = blockIdx.y * 1024 + it * 128;
        const int ct0   = cbase >> 4;    // first 16-col tile of this iter

        int collab[8];
        #pragma unroll
        for (int tc = 0; tc < 8; ++tc) collab[tc] = labels[cbase + tc * 16 + c];

        float4v acc[2][8];
        #pragma unroll
        for (int tr = 0; tr < 2; ++tr)
            #pragma unroll
            for (int tc = 0; tc < 8; ++tc) {
                float4v z = {0.f, 0.f, 0.f, 0.f};
                acc[tr][tc] = z;
            }

        // ---- MFMA: 32 coalesced B-frag loads + 64 MFMA per iter ----
        #pragma unroll
        for (int ks = 0; ks < 4; ++ks) {
            #pragma unroll
            for (int tc = 0; tc < 8; ++tc) {
                short8 b = Bf[(((ct0 + tc) * 4 + ks) << 6) + lane];
                #pragma unroll
                for (int tr = 0; tr < 2; ++tr)
                    acc[tr][tc] = __builtin_amdgcn_mfma_f32_16x16x32_bf16(
                        afrag[tr][ks], b, acc[tr][tc], 0, 0, 0);
            }
        }

        // ---- epilogue: exp2, diagonal/label masking, per-row accumulate ----
        #pragma unroll
        for (int tr = 0; tr < 2; ++tr) {
            const int rtile = rw + tr * 16;
            #pragma unroll
            for (int tc = 0; tc < 8; ++tc) {
                const bool diag_tile = (rtile == cbase + tc * 16);  // wave-uniform
                const int lc = collab[tc];
                #pragma unroll
                for (int reg = 0; reg < 4; ++reg) {
                    float v = EXP2(acc[tr][tc][reg]);
                    if (diag_tile && (q * 4 + reg) == c) v = 0.f;  // r == c
                    tot_a[tr][reg] += v;
                    if (rowlab[tr][reg] == lc) pos_a[tr][reg] += v;
                }
            }
        }
    }

    // ---- row sums: reduce over the 16 column-lanes, one atomic per row ----
    #pragma unroll
    for (int tr = 0; tr < 2; ++tr)
        #pragma unroll
        for (int reg = 0; reg < 4; ++reg) {
            float tt = tot_a[tr][reg];
            float pp = pos_a[tr][reg];
            #pragma unroll
            for (int m = 1; m < 16; m <<= 1) {
                tt += __shfl_xor(tt, m, 64);
                pp += __shfl_xor(pp, m, 64);
            }
            if (c == 0) {
                const int r = rw + tr * 16 + q * 4 + reg;
                atomicAdd(&tot[r], tt);
                atomicAdd(&pos[r], pp);
            }
        }

    // ---- last-block finalize: completion-wait + relaxed ticket (NO cache ops)
    asm volatile("s_waitcnt vmcnt(0)" ::: "memory");  // our atomics committed
    __syncthreads();
    if (tid == 0)
        s_ticket = __hip_atomic_fetch_add(ticket, 1, __ATOMIC_RELAXED,
                                          __HIP_MEMORY_SCOPE_AGENT);
    __syncthreads();
    if (s_ticket != NBLK - 1) return;

    float lsum = 0.f, lcnt = 0.f;
    #pragma unroll 4
    for (int i = tid; i < N; i += 256) {
        const float tt = __hip_atomic_load(&tot[i], __ATOMIC_RELAXED,
                                           __HIP_MEMORY_SCOPE_AGENT);
        const float pp = __hip_atomic_load(&pos[i], __ATOMIC_RELAXED,
                                           __HIP_MEMORY_SCOPE_AGENT);
        const float loss = -__logf(pp / (tt + 1e-8f) + 1e-8f);
        if (pp > 0.f) { lsum += loss; lcnt += 1.f; }   // valid <=> pos>0
    }
    #pragma unroll
    for (int m = 1; m < 64; m <<= 1) {
        lsum += __shfl_xor(lsum, m, 64);
        lcnt += __shfl_xor(lcnt, m, 64);
    }
    if (lane == 0) { sred[0][wave] = lsum; sred[1][wave] = lcnt; }
    __syncthreads();
    if (tid == 0) {
        const float s = sred[0][0] + sred[0][1] + sred[0][2] + sred[0][3];
        const float n = sred[1][0] + sred[1][1] + sred[1][2] + sred[1][3];
        out[0] = (n > 0.f) ? s / fmaxf(n, 1.f) : 0.f;
    }
}

extern "C" void kernel_launch(void* const* d_in, const int* in_sizes, int n_in,
                              void* d_out, int out_size, void* d_ws, size_t ws_size,
                              hipStream_t stream) {
    const float* emb  = (const float*)d_in[0];
    const int* labels = (const int*)d_in[1];
    unsigned short* bfBf = (unsigned short*)d_ws;                      // 2 MB
    unsigned short* bfAf = bfBf + (size_t)N * D;                       // 2 MB
    float* tot    = (float*)(bfAf + (size_t)N * D);
    float* pos    = tot + N;
    int*   ticket = (int*)(pos + N);

    cl_prep<<<512, 256, 0, stream>>>(emb, bfBf, bfAf, tot, ticket);
    cl_main<<<dim3(NBX, NBY), 256, 0, stream>>>(bfAf, bfBf, labels, tot, pos,
                                                ticket, (float*)d_out);
}